// Round 13
// baseline (104.709 us; speedup 1.0000x reference)
//
#include <hip/hip_runtime.h>
#include <cmath>

#define EMBED 1024
#define HEADS 16
#define HDIM  64
#define BATCH 2
#define SEQ   2048
#define MTOT  (BATCH*SEQ)   // 4096
#define KDIM  1024

typedef __attribute__((ext_vector_type(8))) short bf16x8;
typedef __attribute__((ext_vector_type(4))) float fx4;

#define MFMA(a,b,c) __builtin_amdgcn_mfma_f32_16x16x32_bf16((a),(b),(c),0,0,0)

__device__ __forceinline__ unsigned short f2bf(float x) {
    unsigned u = __float_as_uint(x);
    unsigned r = (u + 0x7FFFu + ((u >> 16) & 1u)) >> 16;
    return (unsigned short)r;
}
__device__ __forceinline__ float bf2f(unsigned short h) {
    return __uint_as_float(((unsigned)h) << 16);
}
// ushort index of element (row, e) in a [rows][64] bf16 tile, XOR-swizzled in 8-elem groups
__device__ __forceinline__ int swz_grp(int row, int grp) {  // grp = 16B group 0..7
    return row * 64 + ((grp ^ (row & 7)) << 3);
}
__device__ __forceinline__ void gload16(const void* g, void* l) {
    __builtin_amdgcn_global_load_lds((const __attribute__((address_space(1))) void*)g,
                                     (__attribute__((address_space(3))) void*)l, 16, 0, 0);
}
__device__ __forceinline__ float dpp_qswap(float x) {   // quad_perm [1,0,3,2]
    return __int_as_float(__builtin_amdgcn_mov_dpp(__float_as_int(x), 0xB1, 0xF, 0xF, true));
}

#define C2S 0.18033688f   // 0.125 * log2(e), folded into Q at projection time

// ---------------------------------------------------------------------------
// merged prep: blocks [0,2048) split X->Xh; blocks [2048,3072) transpose W
// to hi-only bf16 planes (Wq,Wk,Wv -> WtH + z*1M; Wo -> WtOh).
// ---------------------------------------------------------------------------
__global__ __launch_bounds__(256)
void prep(const float* __restrict__ X,
          const float* __restrict__ Wq, const float* __restrict__ Wk,
          const float* __restrict__ Wv, const float* __restrict__ Wo,
          unsigned short* __restrict__ Xh,
          unsigned short* __restrict__ WtH, unsigned short* __restrict__ WtOh)
{
    const int bid = blockIdx.x;
    const int tid = threadIdx.x;
    if (bid < 2048) {                    // ---- X -> hi bf16 plane ----
        int i = (bid * 256 + tid) * 8;
        float4 a = *(const float4*)(X + i);
        float4 b = *(const float4*)(X + i + 4);
        bf16x8 h;
        h[0] = (short)f2bf(a.x); h[1] = (short)f2bf(a.y);
        h[2] = (short)f2bf(a.z); h[3] = (short)f2bf(a.w);
        h[4] = (short)f2bf(b.x); h[5] = (short)f2bf(b.y);
        h[6] = (short)f2bf(b.z); h[7] = (short)f2bf(b.w);
        *(bf16x8*)(Xh + i) = h;
        return;
    }
    // ---- W transpose (hi only) ----
    const int u = bid - 2048;            // 0..1023
    const int z = u >> 8;
    const float* W = (z == 0) ? Wq : (z == 1) ? Wk : (z == 2) ? Wv : Wo;
    unsigned short* Th = (z < 3) ? WtH + (size_t)z * 1048576 : WtOh;
    const int k0 = ((u >> 4) & 15) * 64, n0 = (u & 15) * 64;

    __shared__ float t[64][65];
    #pragma unroll
    for (int it = 0; it < 4; ++it) {
        int v2 = tid + it * 256;
        int r = v2 >> 4, c4 = (v2 & 15) << 2;
        float4 v = *(const float4*)(W + (size_t)(k0 + r) * EMBED + n0 + c4);
        t[r][c4] = v.x; t[r][c4 + 1] = v.y; t[r][c4 + 2] = v.z; t[r][c4 + 3] = v.w;
    }
    __syncthreads();
    #pragma unroll
    for (int it = 0; it < 4; ++it) {
        int v2 = tid + it * 256;
        int r = v2 >> 4, c4 = (v2 & 15) << 2;   // r = n-local, c4 = k-local
        ushort4 h;
        h.x = f2bf(t[c4 + 0][r]);
        h.y = f2bf(t[c4 + 1][r]);
        h.z = f2bf(t[c4 + 2][r]);
        h.w = f2bf(t[c4 + 3][r]);
        *(ushort4*)(Th + (size_t)(n0 + r) * EMBED + k0 + c4) = h;
    }
}

// ---------------------------------------------------------------------------
// uniform single-pass QKV GEMM, tile 128x128.  grid (256, 3).
// 4 waves 2x2, wave = 64x64.  C = Xh * Wh + b.  LDS 32KB, 3 blocks/CU.
// y=0: Q*C2S -> [B,H,S,D]; y=1: K -> [B,H,S,D]; y=2: V -> ^T kv-permuted.
// ---------------------------------------------------------------------------
__global__ __launch_bounds__(256, 3)
void gemm_qkv(const unsigned short* __restrict__ Xh,
              const unsigned short* __restrict__ WtH,
              const float* __restrict__ bq, const float* __restrict__ bk,
              const float* __restrict__ bv,
              unsigned short* __restrict__ Qh, unsigned short* __restrict__ Khi,
              unsigned short* __restrict__ Vhi)
{
    __shared__ unsigned short Ah[8192];   // 128 m x 64 k
    __shared__ unsigned short Bh[8192];   // 128 n x 64 k

    const int tid = threadIdx.x, lane = tid & 63, w = tid >> 6;
    const int wm = w >> 1, wn = w & 1;
    const int which = blockIdx.y;
    const int lin = (blockIdx.x & 7) * 32 + (blockIdx.x >> 3);   // XCD swizzle
    const int m0 = (lin >> 3) * 128, n0 = (lin & 7) * 128;

    const char* aB = (const char*)(Xh + (size_t)m0 * KDIM);
    const char* bB = (const char*)(WtH + (size_t)which * 1048576 + (size_t)n0 * KDIM);

    auto stageA = [&](int kt) {
        #pragma unroll
        for (int i = 0; i < 4; ++i) {
            int uw = (i << 12) + (w << 10);
            int u  = uw + (lane << 4);
            int row = u >> 7, grp = (u >> 4) & 7;
            size_t gb = (size_t)row * (KDIM * 2) + (size_t)kt * 128 + ((grp ^ (row & 7)) << 4);
            gload16(aB + gb, (char*)Ah + uw);
        }
    };
    auto stageB = [&](int kt) {
        #pragma unroll
        for (int i = 0; i < 4; ++i) {
            int uw = (i << 12) + (w << 10);
            int u  = uw + (lane << 4);
            int row = u >> 7, grp = (u >> 4) & 7;
            size_t gb = (size_t)row * (KDIM * 2) + (size_t)kt * 128 + ((grp ^ (row & 7)) << 4);
            gload16(bB + gb, (char*)Bh + uw);
        }
    };

    const fx4 zero4 = {0.f, 0.f, 0.f, 0.f};
    fx4 acc[4][4];
    #pragma unroll
    for (int i = 0; i < 4; ++i)
        #pragma unroll
        for (int j = 0; j < 4; ++j) acc[i][j] = zero4;

    for (int kt = 0; kt < KDIM / 64; ++kt) {
        __syncthreads();
        stageA(kt);
        stageB(kt);
        __syncthreads();
        #pragma unroll
        for (int kh = 0; kh < 2; ++kh) {
            const int grp = kh * 4 + (lane >> 4);
            bf16x8 ah[4], bh4[4];
            #pragma unroll
            for (int mi = 0; mi < 4; ++mi)
                ah[mi] = *(const bf16x8*)(Ah + swz_grp(wm * 64 + mi * 16 + (lane & 15), grp));
            #pragma unroll
            for (int ni = 0; ni < 4; ++ni)
                bh4[ni] = *(const bf16x8*)(Bh + swz_grp(wn * 64 + ni * 16 + (lane & 15), grp));
            #pragma unroll
            for (int mi = 0; mi < 4; ++mi)
                #pragma unroll
                for (int ni = 0; ni < 4; ++ni)
                    acc[mi][ni] = MFMA(ah[mi], bh4[ni], acc[mi][ni]);
        }
    }

    const float* bias = (which == 0) ? bq : (which == 1) ? bk : bv;
    #pragma unroll
    for (int mi = 0; mi < 4; ++mi)
        #pragma unroll
        for (int ni = 0; ni < 4; ++ni) {
            const int n = n0 + wn * 64 + ni * 16 + (lane & 15);
            const float bb = bias[n];
            const int hh = n >> 6, d = n & 63;
            if (which < 2) {
                unsigned short* plane = (which == 0) ? Qh : Khi;
                #pragma unroll
                for (int reg = 0; reg < 4; ++reg) {
                    const int m = m0 + wm * 64 + mi * 16 + (lane >> 4) * 4 + reg;
                    const int b = m >> 11, s = m & (SEQ - 1);
                    float val = acc[mi][ni][reg] + bb;
                    if (which == 0) val *= C2S;          // fold softmax scale into Q
                    plane[((size_t)(b * HEADS + hh) * SEQ + s) * HDIM + d] = f2bf(val);
                }
            } else {
                const int m = m0 + wm * 64 + mi * 16 + (lane >> 4) * 4;
                const int b = m >> 11, s = m & (SEQ - 1);
                const int sl = s & 63;
                // kv bit-permutation within the 64-tile (s&3 == 0 here):
                const int c = (sl & 32) | ((sl & 12) << 1) | ((sl & 16) >> 2);
                ushort4 o;
                o.x = f2bf(acc[mi][ni][0] + bb);
                o.y = f2bf(acc[mi][ni][1] + bb);
                o.z = f2bf(acc[mi][ni][2] + bb);
                o.w = f2bf(acc[mi][ni][3] + bb);
                *(ushort4*)(Vhi + ((size_t)(b * HEADS + hh) * HDIM + d) * SEQ
                            + (s & ~63) + c) = o;
            }
        }
}

// ---------------------------------------------------------------------------
// output projection, tile 128x128: C = AOh * WoH + bo, fp32 out.  grid 256.
// Same structure as gemm_qkv.  LDS 32KB, 3 blocks/CU.
// ---------------------------------------------------------------------------
__global__ __launch_bounds__(256, 3)
void gemm_ao(const unsigned short* __restrict__ AOh,
             const unsigned short* __restrict__ Bgh,
             const float* __restrict__ bias, float* __restrict__ Cf)
{
    __shared__ unsigned short Ah[8192];
    __shared__ unsigned short Bh[8192];

    const int tid = threadIdx.x, lane = tid & 63, w = tid >> 6;
    const int wm = w >> 1, wn = w & 1;
    const int lin = (blockIdx.x & 7) * 32 + (blockIdx.x >> 3);   // XCD swizzle
    const int m0 = (lin >> 3) * 128, n0 = (lin & 7) * 128;

    const char* aB = (const char*)(AOh + (size_t)m0 * KDIM);
    const char* bB = (const char*)(Bgh + (size_t)n0 * KDIM);

    auto stageA = [&](int kt) {
        #pragma unroll
        for (int i = 0; i < 4; ++i) {
            int uw = (i << 12) + (w << 10);
            int u  = uw + (lane << 4);
            int row = u >> 7, grp = (u >> 4) & 7;
            size_t gb = (size_t)row * (KDIM * 2) + (size_t)kt * 128 + ((grp ^ (row & 7)) << 4);
            gload16(aB + gb, (char*)Ah + uw);
        }
    };
    auto stageB = [&](int kt) {
        #pragma unroll
        for (int i = 0; i < 4; ++i) {
            int uw = (i << 12) + (w << 10);
            int u  = uw + (lane << 4);
            int row = u >> 7, grp = (u >> 4) & 7;
            size_t gb = (size_t)row * (KDIM * 2) + (size_t)kt * 128 + ((grp ^ (row & 7)) << 4);
            gload16(bB + gb, (char*)Bh + uw);
        }
    };

    const fx4 zero4 = {0.f, 0.f, 0.f, 0.f};
    fx4 acc[4][4];
    #pragma unroll
    for (int i = 0; i < 4; ++i)
        #pragma unroll
        for (int j = 0; j < 4; ++j) acc[i][j] = zero4;

    for (int kt = 0; kt < KDIM / 64; ++kt) {
        __syncthreads();
        stageA(kt);
        stageB(kt);
        __syncthreads();
        #pragma unroll
        for (int kh = 0; kh < 2; ++kh) {
            const int grp = kh * 4 + (lane >> 4);
            bf16x8 ah[4], bh4[4];
            #pragma unroll
            for (int mi = 0; mi < 4; ++mi)
                ah[mi] = *(const bf16x8*)(Ah + swz_grp(wm * 64 + mi * 16 + (lane & 15), grp));
            #pragma unroll
            for (int ni = 0; ni < 4; ++ni)
                bh4[ni] = *(const bf16x8*)(Bh + swz_grp(wn * 64 + ni * 16 + (lane & 15), grp));
            #pragma unroll
            for (int mi = 0; mi < 4; ++mi)
                #pragma unroll
                for (int ni = 0; ni < 4; ++ni)
                    acc[mi][ni] = MFMA(ah[mi], bh4[ni], acc[mi][ni]);
        }
    }

    #pragma unroll
    for (int mi = 0; mi < 4; ++mi)
        #pragma unroll
        for (int ni = 0; ni < 4; ++ni) {
            const int n = n0 + wn * 64 + ni * 16 + (lane & 15);
            const float bb = bias[n];
            #pragma unroll
            for (int reg = 0; reg < 4; ++reg) {
                const int m = m0 + wm * 64 + mi * 16 + (lane >> 4) * 4 + reg;
                Cf[(size_t)m * EMBED + n] = acc[mi][ni][reg] + bb;
            }
        }
}

// ---------------------------------------------------------------------------
// Flash attention, 32 q-rows per wave (2 q-frags): K/V LDS fragment reads
// amortize over 2x the MFMA work -> LDS-BW per q halved (the round-12
// bottleneck).  256 threads = 4 waves, block = 128 q, grid 512.
// Fixed-max softmax (scale folded into Q), swapped QK^T, in-register P,
// kv-permuted V.  LDS 32KB dbuf.
// ---------------------------------------------------------------------------
__global__ __launch_bounds__(256, 2)
void attn_mfma(const unsigned short* __restrict__ Qh,
               const unsigned short* __restrict__ Khi,
               const unsigned short* __restrict__ Vhi, unsigned short* __restrict__ AOh)
{
    __shared__ unsigned short Ks[2][4096];   // K hi, dbuf
    __shared__ unsigned short Vs[2][4096];   // V hi (kv-permuted), dbuf

    const int tid = threadIdx.x, lane = tid & 63, w = tid >> 6;   // w 0..3
    // XCD-local mapping: 4 bh per XCD
    const int xcd = blockIdx.x & 7, loc = blockIdx.x >> 3;        // loc 0..63
    const int bh = xcd * 4 + (loc >> 4);
    const int q0 = (loc & 15) * 128;
    const size_t qkBase = (size_t)bh * SEQ * HDIM;

    auto stageKV = [&](int kv0, int buf) {
        const char* baseK = (const char*)(Khi + qkBase + (size_t)kv0 * HDIM);
        const char* baseV = (const char*)(Vhi + (size_t)bh * HDIM * SEQ + kv0);
        #pragma unroll
        for (int i = 0; i < 2; ++i) {
            int uw = (i << 12) + (w << 10);
            int u  = uw + (lane << 4);
            int row = u >> 7, grp = (u >> 4) & 7;
            size_t gk = (size_t)row * 128 + ((grp ^ (row & 7)) << 4);
            size_t gv = (size_t)row * (SEQ * 2) + ((grp ^ (row & 7)) << 4);
            gload16(baseK + gk, (char*)Ks[buf] + uw);
            gload16(baseV + gv, (char*)Vs[buf] + uw);
        }
    };

    // ---- Q fragments straight from global (B-operand; col = q) ----
    bf16x8 qf[2][2];   // [kh][mi]
    #pragma unroll
    for (int kh = 0; kh < 2; ++kh)
        #pragma unroll
        for (int mi = 0; mi < 2; ++mi) {
            const int row = q0 + w * 32 + mi * 16 + (lane & 15);
            const int grp = kh * 4 + (lane >> 4);
            qf[kh][mi] = *(const bf16x8*)(Qh + qkBase + (size_t)row * HDIM + grp * 8);
        }

    const fx4 zero4 = {0.f, 0.f, 0.f, 0.f};
    fx4 acco[2][4];          // [mi][df]
    fx4 accl[2] = {zero4, zero4};
    #pragma unroll
    for (int mi = 0; mi < 2; ++mi)
        #pragma unroll
        for (int df = 0; df < 4; ++df) acco[mi][df] = zero4;

    bf16x8 ones;
    #pragma unroll
    for (int i = 0; i < 8; ++i) ones[i] = (short)0x3F80;   // bf16 1.0

    stageKV(0, 0);
    __syncthreads();

    for (int t = 0; t < 32; ++t) {
        const int cur = t & 1;
        if (t < 31) stageKV((t + 1) * 64, cur ^ 1);   // async, in flight across compute

        // ---- QK^T swapped: s4[mi][kvf] = K*Q -> row=kv, col=q ----
        fx4 s4[2][4];
        #pragma unroll
        for (int mi = 0; mi < 2; ++mi)
            #pragma unroll
            for (int nf = 0; nf < 4; ++nf) s4[mi][nf] = zero4;
        __builtin_amdgcn_s_setprio(1);
        #pragma unroll
        for (int kh = 0; kh < 2; ++kh) {
            const int grp = kh * 4 + (lane >> 4);
            bf16x8 kf[4];
            #pragma unroll
            for (int nf = 0; nf < 4; ++nf)
                kf[nf] = *(const bf16x8*)(Ks[cur] + swz_grp(nf * 16 + (lane & 15), grp));
            #pragma unroll
            for (int mi = 0; mi < 2; ++mi)
                #pragma unroll
                for (int nf = 0; nf < 4; ++nf)
                    s4[mi][nf] = MFMA(kf[nf], qf[kh][mi], s4[mi][nf]);
        }
        __builtin_amdgcn_s_setprio(0);

        // ---- softmax numerator + lane-local pack, per q-frag ----
        bf16x8 pa[2][2];   // [mi][t2]
        #pragma unroll
        for (int mi = 0; mi < 2; ++mi) {
            float p[4][4];
            #pragma unroll
            for (int kvf = 0; kvf < 4; ++kvf)
                #pragma unroll
                for (int reg = 0; reg < 4; ++reg) {
                    float e;
                    asm("v_exp_f32 %0, %1\n\ts_nop 0" : "=v"(e) : "v"(s4[mi][kvf][reg]));
                    p[kvf][reg] = e;
                }
            #pragma unroll
            for (int t2 = 0; t2 < 2; ++t2) {
                union { unsigned u[4]; bf16x8 v; } pk;
                asm("v_cvt_pk_bf16_f32 %0, %1, %2" : "=v"(pk.u[0])
                    : "v"(p[2 * t2][0]), "v"(p[2 * t2][1]));
                asm("v_cvt_pk_bf16_f32 %0, %1, %2" : "=v"(pk.u[1])
                    : "v"(p[2 * t2][2]), "v"(p[2 * t2][3]));
                asm("v_cvt_pk_bf16_f32 %0, %1, %2" : "=v"(pk.u[2])
                    : "v"(p[2 * t2 + 1][0]), "v"(p[2 * t2 + 1][1]));
                asm("v_cvt_pk_bf16_f32 %0, %1, %2" : "=v"(pk.u[3])
                    : "v"(p[2 * t2 + 1][2]), "v"(p[2 * t2 + 1][3]));
                pa[mi][t2] = pk.v;
            }
        }

        // ---- PV + row-sum (ones-MFMA); V frags read ONCE, used for both mi ----
        __builtin_amdgcn_s_setprio(1);
        #pragma unroll
        for (int t2 = 0; t2 < 2; ++t2) {
            const int grp = t2 * 4 + (lane >> 4);
            #pragma unroll
            for (int mi = 0; mi < 2; ++mi)
                accl[mi] = MFMA(pa[mi][t2], ones, accl[mi]);
            #pragma unroll
            for (int df = 0; df < 4; ++df) {
                bf16x8 vh = *(const bf16x8*)(Vs[cur] + swz_grp(df * 16 + (lane & 15), grp));
                #pragma unroll
                for (int mi = 0; mi < 2; ++mi)
                    acco[mi][df] = MFMA(pa[mi][t2], vh, acco[mi][df]);
            }
        }
        __builtin_amdgcn_s_setprio(0);

        __syncthreads();   // drains vmcnt (next tile staged) + all cur reads done
    }

    // ---- epilogue: hi-only bf16 concat [B,S,E], pair-packed u32 stores ----
    const int b = bh >> 4, h = bh & 15;
    const int parity = lane & 1;
    #pragma unroll
    for (int mi = 0; mi < 2; ++mi) {
        float inv[4];
        #pragma unroll
        for (int reg = 0; reg < 4; ++reg) inv[reg] = __builtin_amdgcn_rcpf(accl[mi][reg]);
        #pragma unroll
        for (int df = 0; df < 4; ++df) {
            const int d0 = df * 16 + ((lane & 15) & ~1);
            #pragma unroll
            for (int rp = 0; rp < 4; rp += 2) {
                float ve = acco[mi][df][rp]     * inv[rp];
                float vo = acco[mi][df][rp + 1] * inv[rp + 1];
                float e_sw = dpp_qswap(ve), o_sw = dpp_qswap(vo);
                float a  = parity ? o_sw : ve;
                float b2 = parity ? vo   : e_sw;
                unsigned u;
                asm volatile("v_cvt_pk_bf16_f32 %0, %1, %2" : "=v"(u) : "v"(a), "v"(b2));
                const int q = q0 + w * 32 + mi * 16 + (lane >> 4) * 4 + rp + parity;
                *(unsigned int*)(AOh + ((size_t)(b * SEQ + q) * EMBED + h * HDIM + d0)) = u;
            }
        }
    }
}

// ---------------------------------------------------------------------------
extern "C" void kernel_launch(void* const* d_in, const int* in_sizes, int n_in,
                              void* d_out, int out_size, void* d_ws, size_t ws_size,
                              hipStream_t stream)
{
    (void)in_sizes; (void)n_in; (void)out_size; (void)ws_size;

    const float* X  = (const float*)d_in[0];
    const float* Wq = (const float*)d_in[1];
    const float* bq = (const float*)d_in[2];
    const float* Wk = (const float*)d_in[3];
    const float* bk = (const float*)d_in[4];
    const float* Wv = (const float*)d_in[5];
    const float* bv = (const float*)d_in[6];
    const float* Wo = (const float*)d_in[7];
    const float* bo = (const float*)d_in[8];

    // ws: 4 regions of 16MB = 64MB (R_us = 8M ushorts per region)
    const size_t R_us = (size_t)8 * 1024 * 1024;
    unsigned short* us = (unsigned short*)d_ws;
    unsigned short* Qh   = us + 0 * R_us;                 // 8MB
    unsigned short* WtOh = us + 0 * R_us + 4194304;       // R0 upper half (2MB)
    unsigned short* Khi  = us + 1 * R_us;                 // 8MB
    unsigned short* Vhi  = us + 2 * R_us;                 // 8MB (kv-permuted ^T)
    unsigned short* AOh  = us + 3 * R_us;                 // 8MB (after WtH dies)
    unsigned short* WtH  = us + 3 * R_us;                 // 3 hi planes (6MB)
    unsigned short* Xh   = (unsigned short*)d_out;        // d_out dead until gemm_ao

    prep<<<dim3(3072), dim3(256), 0, stream>>>(X, Wq, Wk, Wv, Wo, Xh, WtH, WtOh);

    gemm_qkv<<<dim3(256, 3), dim3(256), 0, stream>>>(Xh, WtH, bq, bk, bv, Qh, Khi, Vhi);

    attn_mfma<<<dim3(512), dim3(256), 0, stream>>>(Qh, Khi, Vhi, AOh);

    gemm_ao<<<dim3(256), dim3(256), 0, stream>>>(AOh, WtOh, bo, (float*)d_out);
}

// Round 14
// 97.458 us; speedup vs baseline: 1.0744x; 1.0744x over previous
//
#include <hip/hip_runtime.h>
#include <cmath>

#define EMBED 1024
#define HEADS 16
#define HDIM  64
#define BATCH 2
#define SEQ   2048
#define MTOT  (BATCH*SEQ)   // 4096
#define KDIM  1024

typedef __attribute__((ext_vector_type(8))) short bf16x8;
typedef __attribute__((ext_vector_type(4))) float fx4;

#define MFMA(a,b,c) __builtin_amdgcn_mfma_f32_16x16x32_bf16((a),(b),(c),0,0,0)

__device__ __forceinline__ unsigned short f2bf(float x) {
    unsigned u = __float_as_uint(x);
    unsigned r = (u + 0x7FFFu + ((u >> 16) & 1u)) >> 16;
    return (unsigned short)r;
}
__device__ __forceinline__ float bf2f(unsigned short h) {
    return __uint_as_float(((unsigned)h) << 16);
}
// ushort index in a [rows][64] bf16 tile, XOR-swizzled in 8-elem groups
__device__ __forceinline__ int swz_grp(int row, int grp) {  // grp 0..7
    return row * 64 + ((grp ^ (row & 7)) << 3);
}
// ushort index in a [rows][128] bf16 tile; XOR swizzle on low 3 bits of grp
__device__ __forceinline__ int swz128(int row, int grp16) { // grp16 0..15
    return row * 128 + ((((grp16) & 8) | (((grp16) & 7) ^ (row & 7))) << 3);
}
__device__ __forceinline__ void gload16(const void* g, void* l) {
    __builtin_amdgcn_global_load_lds((const __attribute__((address_space(1))) void*)g,
                                     (__attribute__((address_space(3))) void*)l, 16, 0, 0);
}
__device__ __forceinline__ float dpp_qswap(float x) {   // quad_perm [1,0,3,2]
    return __int_as_float(__builtin_amdgcn_mov_dpp(__float_as_int(x), 0xB1, 0xF, 0xF, true));
}

#define C2S 0.18033688f   // 0.125 * log2(e), folded into Q at projection time

// ---------------------------------------------------------------------------
// merged prep: blocks [0,2048) split X->Xh; blocks [2048,3072) transpose W
// to hi-only bf16 planes (Wq,Wk,Wv -> WtH + z*1M; Wo -> WtOh).
// ---------------------------------------------------------------------------
__global__ __launch_bounds__(256)
void prep(const float* __restrict__ X,
          const float* __restrict__ Wq, const float* __restrict__ Wk,
          const float* __restrict__ Wv, const float* __restrict__ Wo,
          unsigned short* __restrict__ Xh,
          unsigned short* __restrict__ WtH, unsigned short* __restrict__ WtOh)
{
    const int bid = blockIdx.x;
    const int tid = threadIdx.x;
    if (bid < 2048) {                    // ---- X -> hi bf16 plane ----
        int i = (bid * 256 + tid) * 8;
        float4 a = *(const float4*)(X + i);
        float4 b = *(const float4*)(X + i + 4);
        bf16x8 h;
        h[0] = (short)f2bf(a.x); h[1] = (short)f2bf(a.y);
        h[2] = (short)f2bf(a.z); h[3] = (short)f2bf(a.w);
        h[4] = (short)f2bf(b.x); h[5] = (short)f2bf(b.y);
        h[6] = (short)f2bf(b.z); h[7] = (short)f2bf(b.w);
        *(bf16x8*)(Xh + i) = h;
        return;
    }
    // ---- W transpose (hi only) ----
    const int u = bid - 2048;            // 0..1023
    const int z = u >> 8;
    const float* W = (z == 0) ? Wq : (z == 1) ? Wk : (z == 2) ? Wv : Wo;
    unsigned short* Th = (z < 3) ? WtH + (size_t)z * 1048576 : WtOh;
    const int k0 = ((u >> 4) & 15) * 64, n0 = (u & 15) * 64;

    __shared__ float t[64][65];
    #pragma unroll
    for (int it = 0; it < 4; ++it) {
        int v2 = tid + it * 256;
        int r = v2 >> 4, c4 = (v2 & 15) << 2;
        float4 v = *(const float4*)(W + (size_t)(k0 + r) * EMBED + n0 + c4);
        t[r][c4] = v.x; t[r][c4 + 1] = v.y; t[r][c4 + 2] = v.z; t[r][c4 + 3] = v.w;
    }
    __syncthreads();
    #pragma unroll
    for (int it = 0; it < 4; ++it) {
        int v2 = tid + it * 256;
        int r = v2 >> 4, c4 = (v2 & 15) << 2;   // r = n-local, c4 = k-local
        ushort4 h;
        h.x = f2bf(t[c4 + 0][r]);
        h.y = f2bf(t[c4 + 1][r]);
        h.z = f2bf(t[c4 + 2][r]);
        h.w = f2bf(t[c4 + 3][r]);
        *(ushort4*)(Th + (size_t)(n0 + r) * EMBED + k0 + c4) = h;
    }
}

// ---------------------------------------------------------------------------
// uniform single-pass QKV GEMM, tile 128x128.  grid (256, 3).
// 4 waves 2x2, wave = 64x64.  C = Xh * Wh + b.  LDS 32KB, 3 blocks/CU.
// y=0: Q*C2S -> [B,H,S,D]; y=1: K -> [B,H,S,D]; y=2: V -> ^T kv-permuted.
// ---------------------------------------------------------------------------
__global__ __launch_bounds__(256, 3)
void gemm_qkv(const unsigned short* __restrict__ Xh,
              const unsigned short* __restrict__ WtH,
              const float* __restrict__ bq, const float* __restrict__ bk,
              const float* __restrict__ bv,
              unsigned short* __restrict__ Qh, unsigned short* __restrict__ Khi,
              unsigned short* __restrict__ Vhi)
{
    __shared__ unsigned short Ah[8192];   // 128 m x 64 k
    __shared__ unsigned short Bh[8192];   // 128 n x 64 k

    const int tid = threadIdx.x, lane = tid & 63, w = tid >> 6;
    const int wm = w >> 1, wn = w & 1;
    const int which = blockIdx.y;
    const int lin = (blockIdx.x & 7) * 32 + (blockIdx.x >> 3);   // XCD swizzle
    const int m0 = (lin >> 3) * 128, n0 = (lin & 7) * 128;

    const char* aB = (const char*)(Xh + (size_t)m0 * KDIM);
    const char* bB = (const char*)(WtH + (size_t)which * 1048576 + (size_t)n0 * KDIM);

    auto stageA = [&](int kt) {
        #pragma unroll
        for (int i = 0; i < 4; ++i) {
            int uw = (i << 12) + (w << 10);
            int u  = uw + (lane << 4);
            int row = u >> 7, grp = (u >> 4) & 7;
            size_t gb = (size_t)row * (KDIM * 2) + (size_t)kt * 128 + ((grp ^ (row & 7)) << 4);
            gload16(aB + gb, (char*)Ah + uw);
        }
    };
    auto stageB = [&](int kt) {
        #pragma unroll
        for (int i = 0; i < 4; ++i) {
            int uw = (i << 12) + (w << 10);
            int u  = uw + (lane << 4);
            int row = u >> 7, grp = (u >> 4) & 7;
            size_t gb = (size_t)row * (KDIM * 2) + (size_t)kt * 128 + ((grp ^ (row & 7)) << 4);
            gload16(bB + gb, (char*)Bh + uw);
        }
    };

    const fx4 zero4 = {0.f, 0.f, 0.f, 0.f};
    fx4 acc[4][4];
    #pragma unroll
    for (int i = 0; i < 4; ++i)
        #pragma unroll
        for (int j = 0; j < 4; ++j) acc[i][j] = zero4;

    for (int kt = 0; kt < KDIM / 64; ++kt) {
        __syncthreads();
        stageA(kt);
        stageB(kt);
        __syncthreads();
        #pragma unroll
        for (int kh = 0; kh < 2; ++kh) {
            const int grp = kh * 4 + (lane >> 4);
            bf16x8 ah[4], bh4[4];
            #pragma unroll
            for (int mi = 0; mi < 4; ++mi)
                ah[mi] = *(const bf16x8*)(Ah + swz_grp(wm * 64 + mi * 16 + (lane & 15), grp));
            #pragma unroll
            for (int ni = 0; ni < 4; ++ni)
                bh4[ni] = *(const bf16x8*)(Bh + swz_grp(wn * 64 + ni * 16 + (lane & 15), grp));
            #pragma unroll
            for (int mi = 0; mi < 4; ++mi)
                #pragma unroll
                for (int ni = 0; ni < 4; ++ni)
                    acc[mi][ni] = MFMA(ah[mi], bh4[ni], acc[mi][ni]);
        }
    }

    const float* bias = (which == 0) ? bq : (which == 1) ? bk : bv;
    #pragma unroll
    for (int mi = 0; mi < 4; ++mi)
        #pragma unroll
        for (int ni = 0; ni < 4; ++ni) {
            const int n = n0 + wn * 64 + ni * 16 + (lane & 15);
            const float bb = bias[n];
            const int hh = n >> 6, d = n & 63;
            if (which < 2) {
                unsigned short* plane = (which == 0) ? Qh : Khi;
                #pragma unroll
                for (int reg = 0; reg < 4; ++reg) {
                    const int m = m0 + wm * 64 + mi * 16 + (lane >> 4) * 4 + reg;
                    const int b = m >> 11, s = m & (SEQ - 1);
                    float val = acc[mi][ni][reg] + bb;
                    if (which == 0) val *= C2S;          // fold softmax scale into Q
                    plane[((size_t)(b * HEADS + hh) * SEQ + s) * HDIM + d] = f2bf(val);
                }
            } else {
                const int m = m0 + wm * 64 + mi * 16 + (lane >> 4) * 4;
                const int b = m >> 11, s = m & (SEQ - 1);
                const int sl = s & 63;
                // kv bit-permutation within the 64-tile (s&3 == 0 here):
                const int c = (sl & 32) | ((sl & 12) << 1) | ((sl & 16) >> 2);
                ushort4 o;
                o.x = f2bf(acc[mi][ni][0] + bb);
                o.y = f2bf(acc[mi][ni][1] + bb);
                o.z = f2bf(acc[mi][ni][2] + bb);
                o.w = f2bf(acc[mi][ni][3] + bb);
                *(ushort4*)(Vhi + ((size_t)(b * HEADS + hh) * HDIM + d) * SEQ
                            + (s & ~63) + c) = o;
            }
        }
}

// ---------------------------------------------------------------------------
// output projection, single-pass: C = AOh * WoH + bo, fp32 out.  LDS 24KB.
// (round-12 proven version: tile 128x64, grid 512, 4 blocks/CU)
// ---------------------------------------------------------------------------
__global__ __launch_bounds__(256, 4)
void gemm_ao(const unsigned short* __restrict__ AOh,
             const unsigned short* __restrict__ Bgh,
             const float* __restrict__ bias, float* __restrict__ Cf)
{
    __shared__ unsigned short Ah[8192];
    __shared__ unsigned short Bh[4096];

    const int tid = threadIdx.x, lane = tid & 63, w = tid >> 6;
    const int wm = w >> 1, wn = w & 1;
    const int lin = (blockIdx.x & 7) * 64 + (blockIdx.x >> 3);
    const int m0 = (lin >> 4) * 128, n0 = (lin & 15) * 64;

    const char* aB = (const char*)(AOh + (size_t)m0 * KDIM);
    const char* bB = (const char*)(Bgh + (size_t)n0 * KDIM);

    auto stageA = [&](int kt) {
        #pragma unroll
        for (int i = 0; i < 4; ++i) {
            int uw = (i << 12) + (w << 10);
            int u  = uw + (lane << 4);
            int row = u >> 7, grp = (u >> 4) & 7;
            size_t gb = (size_t)row * (KDIM * 2) + (size_t)kt * 128 + ((grp ^ (row & 7)) << 4);
            gload16(aB + gb, (char*)Ah + uw);
        }
    };
    auto stageB = [&](int kt) {
        #pragma unroll
        for (int i = 0; i < 2; ++i) {
            int uw = (i << 12) + (w << 10);
            int u  = uw + (lane << 4);
            int row = u >> 7, grp = (u >> 4) & 7;
            size_t gb = (size_t)row * (KDIM * 2) + (size_t)kt * 128 + ((grp ^ (row & 7)) << 4);
            gload16(bB + gb, (char*)Bh + uw);
        }
    };

    const fx4 zero4 = {0.f, 0.f, 0.f, 0.f};
    fx4 acc[4][2];
    #pragma unroll
    for (int i = 0; i < 4; ++i) { acc[i][0] = zero4; acc[i][1] = zero4; }

    for (int kt = 0; kt < KDIM / 64; ++kt) {
        __syncthreads();
        stageA(kt);
        stageB(kt);
        __syncthreads();
        #pragma unroll
        for (int kh = 0; kh < 2; ++kh) {
            const int grp = kh * 4 + (lane >> 4);
            bf16x8 ah[4], bh2[2];
            #pragma unroll
            for (int mi = 0; mi < 4; ++mi)
                ah[mi] = *(const bf16x8*)(Ah + swz_grp(wm * 64 + mi * 16 + (lane & 15), grp));
            #pragma unroll
            for (int ni = 0; ni < 2; ++ni)
                bh2[ni] = *(const bf16x8*)(Bh + swz_grp(wn * 32 + ni * 16 + (lane & 15), grp));
            #pragma unroll
            for (int mi = 0; mi < 4; ++mi)
                #pragma unroll
                for (int ni = 0; ni < 2; ++ni)
                    acc[mi][ni] = MFMA(ah[mi], bh2[ni], acc[mi][ni]);
        }
    }

    #pragma unroll
    for (int mi = 0; mi < 4; ++mi)
        #pragma unroll
        for (int ni = 0; ni < 2; ++ni) {
            const int n = n0 + wn * 32 + ni * 16 + (lane & 15);
            const float bb = bias[n];
            #pragma unroll
            for (int reg = 0; reg < 4; ++reg) {
                const int m = m0 + wm * 64 + mi * 16 + (lane >> 4) * 4 + reg;
                Cf[(size_t)m * EMBED + n] = acc[mi][ni][reg] + bb;
            }
        }
}

// ---------------------------------------------------------------------------
// Flash attention, KVBLK=128: halves the barrier count (16 vs 32) to attack
// the per-tile fixed overhead (round-13 finding: time invariant across
// occupancy at KVBLK=64).  256 threads = 4 waves x 32 q, block = 128 q,
// grid 512.  K tile [128][64]; V tile [64][128] (kv-permuted, swz128).
// Fixed-max softmax, swapped QK^T, in-register P.  LDS 64KB -> 2 blocks/CU.
// ---------------------------------------------------------------------------
__global__ __launch_bounds__(256, 2)
void attn_mfma(const unsigned short* __restrict__ Qh,
               const unsigned short* __restrict__ Khi,
               const unsigned short* __restrict__ Vhi, unsigned short* __restrict__ AOh)
{
    __shared__ unsigned short Ks[2][8192];   // K hi [128 kv][64 d], dbuf
    __shared__ unsigned short Vs[2][8192];   // V hi [64 d][128 kv-perm], dbuf

    const int tid = threadIdx.x, lane = tid & 63, w = tid >> 6;   // w 0..3
    const int xcd = blockIdx.x & 7, loc = blockIdx.x >> 3;        // loc 0..63
    const int bh = xcd * 4 + (loc >> 4);
    const int q0 = (loc & 15) * 128;
    const size_t qkBase = (size_t)bh * SEQ * HDIM;

    auto stageKV = [&](int kv0, int buf) {
        const char* baseK = (const char*)(Khi + qkBase + (size_t)kv0 * HDIM);
        const char* baseV = (const char*)(Vhi + (size_t)bh * HDIM * SEQ + kv0);
        #pragma unroll
        for (int i = 0; i < 4; ++i) {
            int uw = (i << 12) + (w << 10);
            int u  = uw + (lane << 4);
            // K: [128 kv][64 d] rows of 128B
            int rowk = u >> 7, grpk = (u >> 4) & 7;
            size_t gk = (size_t)rowk * 128 + ((grpk ^ (rowk & 7)) << 4);
            gload16(baseK + gk, (char*)Ks[buf] + uw);
            // V: [64 d][128 s] rows of 256B; XOR low-3 bits of 16B-group
            int rowv = u >> 8, grpv = (u >> 4) & 15;
            int grpv2 = (grpv & 8) | ((grpv & 7) ^ (rowv & 7));
            size_t gv = (size_t)rowv * (SEQ * 2) + ((size_t)grpv2 << 4);
            gload16(baseV + gv, (char*)Vs[buf] + uw);
        }
    };

    // ---- Q fragments straight from global (B-operand; col = q) ----
    bf16x8 qf[2][2];   // [kh][mi]
    #pragma unroll
    for (int kh = 0; kh < 2; ++kh)
        #pragma unroll
        for (int mi = 0; mi < 2; ++mi) {
            const int row = q0 + w * 32 + mi * 16 + (lane & 15);
            const int grp = kh * 4 + (lane >> 4);
            qf[kh][mi] = *(const bf16x8*)(Qh + qkBase + (size_t)row * HDIM + grp * 8);
        }

    const fx4 zero4 = {0.f, 0.f, 0.f, 0.f};
    fx4 acco[2][4];          // [mi][df]
    fx4 accl[2] = {zero4, zero4};
    #pragma unroll
    for (int mi = 0; mi < 2; ++mi)
        #pragma unroll
        for (int df = 0; df < 4; ++df) acco[mi][df] = zero4;

    bf16x8 ones;
    #pragma unroll
    for (int i = 0; i < 8; ++i) ones[i] = (short)0x3F80;   // bf16 1.0

    stageKV(0, 0);
    __syncthreads();

    for (int t = 0; t < 16; ++t) {
        const int cur = t & 1;
        if (t < 15) stageKV((t + 1) * 128, cur ^ 1);   // async across compute

        // ---- QK^T swapped: s4[mi][nf] = K*Q, nf = kv-frag 0..7 ----
        fx4 s4[2][8];
        #pragma unroll
        for (int mi = 0; mi < 2; ++mi)
            #pragma unroll
            for (int nf = 0; nf < 8; ++nf) s4[mi][nf] = zero4;
        __builtin_amdgcn_s_setprio(1);
        #pragma unroll
        for (int kh = 0; kh < 2; ++kh) {
            const int grp = kh * 4 + (lane >> 4);
            bf16x8 kf[8];
            #pragma unroll
            for (int nf = 0; nf < 8; ++nf)
                kf[nf] = *(const bf16x8*)(Ks[cur] + swz_grp(nf * 16 + (lane & 15), grp));
            #pragma unroll
            for (int mi = 0; mi < 2; ++mi)
                #pragma unroll
                for (int nf = 0; nf < 8; ++nf)
                    s4[mi][nf] = MFMA(kf[nf], qf[kh][mi], s4[mi][nf]);
        }
        __builtin_amdgcn_s_setprio(0);

        // ---- softmax numerator + lane-local pack, per q-frag ----
        bf16x8 pa[2][4];   // [mi][t2], t2 covers kv 32-blocks
        #pragma unroll
        for (int mi = 0; mi < 2; ++mi) {
            float p[8][4];
            #pragma unroll
            for (int kvf = 0; kvf < 8; ++kvf)
                #pragma unroll
                for (int reg = 0; reg < 4; ++reg) {
                    float e;
                    asm("v_exp_f32 %0, %1\n\ts_nop 0" : "=v"(e) : "v"(s4[mi][kvf][reg]));
                    p[kvf][reg] = e;
                }
            #pragma unroll
            for (int t2 = 0; t2 < 4; ++t2) {
                union { unsigned u[4]; bf16x8 v; } pk;
                asm("v_cvt_pk_bf16_f32 %0, %1, %2" : "=v"(pk.u[0])
                    : "v"(p[2 * t2][0]), "v"(p[2 * t2][1]));
                asm("v_cvt_pk_bf16_f32 %0, %1, %2" : "=v"(pk.u[1])
                    : "v"(p[2 * t2][2]), "v"(p[2 * t2][3]));
                asm("v_cvt_pk_bf16_f32 %0, %1, %2" : "=v"(pk.u[2])
                    : "v"(p[2 * t2 + 1][0]), "v"(p[2 * t2 + 1][1]));
                asm("v_cvt_pk_bf16_f32 %0, %1, %2" : "=v"(pk.u[3])
                    : "v"(p[2 * t2 + 1][2]), "v"(p[2 * t2 + 1][3]));
                pa[mi][t2] = pk.v;
            }
        }

        // ---- PV + row-sum; V frags read once, used for both mi ----
        __builtin_amdgcn_s_setprio(1);
        #pragma unroll
        for (int t2 = 0; t2 < 4; ++t2) {
            const int grp16 = t2 * 4 + (lane >> 4);
            #pragma unroll
            for (int mi = 0; mi < 2; ++mi)
                accl[mi] = MFMA(pa[mi][t2], ones, accl[mi]);
            #pragma unroll
            for (int df = 0; df < 4; ++df) {
                bf16x8 vh = *(const bf16x8*)(Vs[cur] + swz128(df * 16 + (lane & 15), grp16));
                #pragma unroll
                for (int mi = 0; mi < 2; ++mi)
                    acco[mi][df] = MFMA(pa[mi][t2], vh, acco[mi][df]);
            }
        }
        __builtin_amdgcn_s_setprio(0);

        __syncthreads();   // drains vmcnt (next tile staged) + all cur reads done
    }

    // ---- epilogue: hi-only bf16 concat [B,S,E], pair-packed u32 stores ----
    const int b = bh >> 4, h = bh & 15;
    const int parity = lane & 1;
    #pragma unroll
    for (int mi = 0; mi < 2; ++mi) {
        float inv[4];
        #pragma unroll
        for (int reg = 0; reg < 4; ++reg) inv[reg] = __builtin_amdgcn_rcpf(accl[mi][reg]);
        #pragma unroll
        for (int df = 0; df < 4; ++df) {
            const int d0 = df * 16 + ((lane & 15) & ~1);
            #pragma unroll
            for (int rp = 0; rp < 4; rp += 2) {
                float ve = acco[mi][df][rp]     * inv[rp];
                float vo = acco[mi][df][rp + 1] * inv[rp + 1];
                float e_sw = dpp_qswap(ve), o_sw = dpp_qswap(vo);
                float a  = parity ? o_sw : ve;
                float b2 = parity ? vo   : e_sw;
                unsigned u;
                asm volatile("v_cvt_pk_bf16_f32 %0, %1, %2" : "=v"(u) : "v"(a), "v"(b2));
                const int q = q0 + w * 32 + mi * 16 + (lane >> 4) * 4 + rp + parity;
                *(unsigned int*)(AOh + ((size_t)(b * SEQ + q) * EMBED + h * HDIM + d0)) = u;
            }
        }
    }
}

// ---------------------------------------------------------------------------
extern "C" void kernel_launch(void* const* d_in, const int* in_sizes, int n_in,
                              void* d_out, int out_size, void* d_ws, size_t ws_size,
                              hipStream_t stream)
{
    (void)in_sizes; (void)n_in; (void)out_size; (void)ws_size;

    const float* X  = (const float*)d_in[0];
    const float* Wq = (const float*)d_in[1];
    const float* bq = (const float*)d_in[2];
    const float* Wk = (const float*)d_in[3];
    const float* bk = (const float*)d_in[4];
    const float* Wv = (const float*)d_in[5];
    const float* bv = (const float*)d_in[6];
    const float* Wo = (const float*)d_in[7];
    const float* bo = (const float*)d_in[8];

    // ws: 4 regions of 16MB = 64MB (R_us = 8M ushorts per region)
    const size_t R_us = (size_t)8 * 1024 * 1024;
    unsigned short* us = (unsigned short*)d_ws;
    unsigned short* Qh   = us + 0 * R_us;                 // 8MB
    unsigned short* WtOh = us + 0 * R_us + 4194304;       // R0 upper half (2MB)
    unsigned short* Khi  = us + 1 * R_us;                 // 8MB
    unsigned short* Vhi  = us + 2 * R_us;                 // 8MB (kv-permuted ^T)
    unsigned short* AOh  = us + 3 * R_us;                 // 8MB (after WtH dies)
    unsigned short* WtH  = us + 3 * R_us;                 // 3 hi planes (6MB)
    unsigned short* Xh   = (unsigned short*)d_out;        // d_out dead until gemm_ao

    prep<<<dim3(3072), dim3(256), 0, stream>>>(X, Wq, Wk, Wv, Wo, Xh, WtH, WtOh);

    gemm_qkv<<<dim3(256, 3), dim3(256), 0, stream>>>(Xh, WtH, bq, bk, bv, Qh, Khi, Vhi);

    attn_mfma<<<dim3(512), dim3(256), 0, stream>>>(Qh, Khi, Vhi, AOh);

    gemm_ao<<<dim3(512), dim3(256), 0, stream>>>(AOh, WtOh, bo, (float*)d_out);
}